// Round 3
// baseline (110.708 us; speedup 1.0000x reference)
//
#include <hip/hip_runtime.h>
#include <hip/hip_bf16.h>

typedef __attribute__((ext_vector_type(8))) short bf16x8;
typedef __attribute__((ext_vector_type(4))) float f32x4;

#define TT 128
#define DD 256
#define BK 64
#define BPAN 16384   // byte offset of B panel in LDS

__device__ __forceinline__ unsigned short f2bf(float f) {
  unsigned int x = __float_as_uint(f);
  x += 0x7fffu + ((x >> 16) & 1u);          // round-to-nearest-even
  return (unsigned short)(x >> 16);
}

__device__ __forceinline__ bf16x8 pack8(float4 lo, float4 hi) {
  bf16x8 v;
  v[0] = (short)f2bf(lo.x); v[1] = (short)f2bf(lo.y);
  v[2] = (short)f2bf(lo.z); v[3] = (short)f2bf(lo.w);
  v[4] = (short)f2bf(hi.x); v[5] = (short)f2bf(hi.y);
  v[6] = (short)f2bf(hi.z); v[7] = (short)f2bf(hi.w);
  return v;
}

// One workgroup per (i,j) pair: computes dense_similarity[i,j].
// LDS kept at exactly 64 KiB: GEMM phase uses A/B bf16 panels (32 KiB),
// pooling phase reuses the whole buffer as the 128x128 f32 S tile (64 KiB,
// XOR-swizzled ^((row&7)<<4) instead of padding).
__global__ __launch_bounds__(512, 4) void pair_kernel(
    const float* __restrict__ video, const float* __restrict__ wifi,
    float* __restrict__ dense) {
  __shared__ __align__(16) char lds[65536];
  const int tid = threadIdx.x;
  const int bid = blockIdx.x;
  const int bi = bid >> 6, bj = bid & 63;
  const float* __restrict__ Ag = video + (size_t)bi * (TT * DD);
  const float* __restrict__ Bg = wifi  + (size_t)bj * (TT * DD);

  const int wid = tid >> 6, l = tid & 63;
  const int l15 = l & 15;
  const int R   = (wid >> 1) * 32;          // wave's video-row base
  const int Cc  = (wid & 1) * 64;           // wave's wifi-col base
  const int xr  = (l15 & 7) << 4;           // panel swizzle for frag rows
  const int lhi16 = (l >> 4) * 16;          // lane's 16B k-chunk

  // staging: thread t converts 16 f32 -> 16 bf16 of one panel row chunk
  const int srow  = tid >> 2;               // 0..127
  const int scolb = (tid & 3) * 32;         // byte col within 128B panel row
  const int sswz  = (srow & 7) << 4;
  const int sb0 = srow * 128 + ((scolb)      ^ sswz);
  const int sb1 = srow * 128 + ((scolb + 16) ^ sswz);

  f32x4 acc[2][4];
#pragma unroll
  for (int m = 0; m < 2; ++m)
#pragma unroll
    for (int n = 0; n < 4; ++n) acc[m][n] = (f32x4){0.f, 0.f, 0.f, 0.f};

  const int arow0 = (R + l15) * 128;
  const int arow1 = (R + 16 + l15) * 128;
  const int brow0 = (Cc +  0 + l15) * 128 + BPAN;
  const int brow1 = (Cc + 16 + l15) * 128 + BPAN;
  const int brow2 = (Cc + 32 + l15) * 128 + BPAN;
  const int brow3 = (Cc + 48 + l15) * 128 + BPAN;

  for (int kp = 0; kp < 4; ++kp) {
    // global loads first (no LDS dependency) so they overlap the sync
    const float* pa = Ag + srow * DD + kp * BK + (tid & 3) * 16;
    const float* pb = Bg + srow * DD + kp * BK + (tid & 3) * 16;
    float4 a0 = *(const float4*)(pa);
    float4 a1 = *(const float4*)(pa + 4);
    float4 a2 = *(const float4*)(pa + 8);
    float4 a3 = *(const float4*)(pa + 12);
    float4 b0 = *(const float4*)(pb);
    float4 b1 = *(const float4*)(pb + 4);
    float4 b2 = *(const float4*)(pb + 8);
    float4 b3 = *(const float4*)(pb + 12);
    if (kp) __syncthreads();                // prev panel fully consumed
    *(bf16x8*)(lds + sb0)        = pack8(a0, a1);
    *(bf16x8*)(lds + sb1)        = pack8(a2, a3);
    *(bf16x8*)(lds + BPAN + sb0) = pack8(b0, b1);
    *(bf16x8*)(lds + BPAN + sb1) = pack8(b2, b3);
    __syncthreads();                        // panel ready

#pragma unroll
    for (int ks = 0; ks < 2; ++ks) {
      const int ko = (ks * 64 + lhi16) ^ xr;
      bf16x8 fa0 = *(const bf16x8*)(lds + arow0 + ko);
      bf16x8 fa1 = *(const bf16x8*)(lds + arow1 + ko);
      bf16x8 fb0 = *(const bf16x8*)(lds + brow0 + ko);
      bf16x8 fb1 = *(const bf16x8*)(lds + brow1 + ko);
      bf16x8 fb2 = *(const bf16x8*)(lds + brow2 + ko);
      bf16x8 fb3 = *(const bf16x8*)(lds + brow3 + ko);
      acc[0][0] = __builtin_amdgcn_mfma_f32_16x16x32_bf16(fa0, fb0, acc[0][0], 0, 0, 0);
      acc[0][1] = __builtin_amdgcn_mfma_f32_16x16x32_bf16(fa0, fb1, acc[0][1], 0, 0, 0);
      acc[0][2] = __builtin_amdgcn_mfma_f32_16x16x32_bf16(fa0, fb2, acc[0][2], 0, 0, 0);
      acc[0][3] = __builtin_amdgcn_mfma_f32_16x16x32_bf16(fa0, fb3, acc[0][3], 0, 0, 0);
      acc[1][0] = __builtin_amdgcn_mfma_f32_16x16x32_bf16(fa1, fb0, acc[1][0], 0, 0, 0);
      acc[1][1] = __builtin_amdgcn_mfma_f32_16x16x32_bf16(fa1, fb1, acc[1][1], 0, 0, 0);
      acc[1][2] = __builtin_amdgcn_mfma_f32_16x16x32_bf16(fa1, fb2, acc[1][2], 0, 0, 0);
      acc[1][3] = __builtin_amdgcn_mfma_f32_16x16x32_bf16(fa1, fb3, acc[1][3], 0, 0, 0);
    }
  }
  __syncthreads();   // all frag reads done before S overwrites the panels

  // ---- write S (f32, [128][128], swizzled) ----
  // C/D layout (16x16x32): col = lane&15, row = (lane>>4)*4 + reg  [m89]
  {
    const int rbase = R + (l >> 4) * 4;
    const int cbase = Cc + l15;
#pragma unroll
    for (int m = 0; m < 2; ++m)
#pragma unroll
      for (int n = 0; n < 4; ++n)
#pragma unroll
        for (int reg = 0; reg < 4; ++reg) {
          const int row = rbase + m * 16 + reg;
          const int col = cbase + n * 16;
          *(float*)(lds + row * 512 + ((col * 4) ^ ((row & 7) << 4))) =
              acc[m][n][reg];
        }
  }
  __syncthreads();

  // ---- row (v2w) and col (w2v) soft pooling, 4 lanes per row/col ----
  const int r = tid >> 2, g = tid & 3;
  float svv, sww;
  {
    float v[32];
    float mx = -3.4e38f;
    const int rswz = (r & 7) << 4;
#pragma unroll
    for (int c = 0; c < 32; ++c) {
      const int col = g + 4 * c;
      v[c] = *(const float*)(lds + r * 512 + ((col * 4) ^ rswz));
      mx = fmaxf(mx, v[c]);
    }
    mx = fmaxf(mx, __shfl_xor(mx, 1));
    mx = fmaxf(mx, __shfl_xor(mx, 2));
    float se = 0.f, sev = 0.f;
#pragma unroll
    for (int c = 0; c < 32; ++c) {
      float e = __expf((v[c] - mx) * 2.0f);   // /tau = *2
      se += e; sev += e * v[c];
    }
    se  += __shfl_xor(se, 1);  se  += __shfl_xor(se, 2);
    sev += __shfl_xor(sev, 1); sev += __shfl_xor(sev, 2);
    svv = sev / se;
  }
  {
    float v[32];
    float mx = -3.4e38f;
#pragma unroll
    for (int c = 0; c < 32; ++c) {
      const int row = g + 4 * c;
      v[c] = *(const float*)(lds + row * 512 + ((r * 4) ^ ((row & 7) << 4)));
      mx = fmaxf(mx, v[c]);
    }
    mx = fmaxf(mx, __shfl_xor(mx, 1));
    mx = fmaxf(mx, __shfl_xor(mx, 2));
    float se = 0.f, sev = 0.f;
#pragma unroll
    for (int c = 0; c < 32; ++c) {
      float e = __expf((v[c] - mx) * 2.0f);
      se += e; sev += e * v[c];
    }
    se  += __shfl_xor(se, 1);  se  += __shfl_xor(se, 2);
    sev += __shfl_xor(sev, 1); sev += __shfl_xor(sev, 2);
    sww = sev / se;
  }
  __syncthreads();   // S fully consumed; safe to clobber with sv/sw
  if (g == 0) {
    *(float*)(lds + r * 4)       = svv;   // sv[128] at bytes 0..511
    *(float*)(lds + 512 + r * 4) = sww;   // sw[128] at bytes 512..1023
  }
  __syncthreads();

  // ---- frame-level softmax pooling -> scalars ----
  if (wid < 2) {
    const float* arr = (const float*)(lds + wid * 512);
    float a0 = arr[l], a1 = arr[l + 64];
    float mx = fmaxf(a0, a1);
#pragma unroll
    for (int s = 1; s < 64; s <<= 1) mx = fmaxf(mx, __shfl_xor(mx, s));
    float e0 = __expf((a0 - mx) * 2.0f), e1 = __expf((a1 - mx) * 2.0f);
    float se = e0 + e1, sev = e0 * a0 + e1 * a1;
#pragma unroll
    for (int s = 1; s < 64; s <<= 1) { se += __shfl_xor(se, s); sev += __shfl_xor(sev, s); }
    if (l == 0) *(float*)(lds + 1024 + wid * 4) = sev / se;
  }
  __syncthreads();
  if (tid == 0)
    dense[bid] = 0.5f * (*(const float*)(lds + 1024) + *(const float*)(lds + 1028));
}

// Label-smoothed symmetric CE over the 64x64 dense-similarity matrix.
// Output is FLOAT32 (reference returns jnp.float32 scalar).
__global__ __launch_bounds__(64) void loss_kernel(
    const float* __restrict__ dense, const float* __restrict__ scalep,
    float* __restrict__ out) {
  const int i = threadIdx.x;   // 0..63 — row i and col i
  const float sc = fminf(scalep[0], 40.0f);
  float mxr = -3.4e38f, mxc = -3.4e38f;
  for (int j = 0; j < 64; ++j) {
    mxr = fmaxf(mxr, sc * dense[i * 64 + j]);
    mxc = fmaxf(mxc, sc * dense[j * 64 + i]);
  }
  float ser = 0.f, sec = 0.f, slr = 0.f, slc = 0.f;
  for (int j = 0; j < 64; ++j) {
    float zr = sc * dense[i * 64 + j];
    float zc = sc * dense[j * 64 + i];
    ser += __expf(zr - mxr); sec += __expf(zc - mxc);
    slr += zr;               slc += zc;
  }
  const float lser = mxr + logf(ser);
  const float lsec = mxc + logf(sec);
  const float zd = sc * dense[i * 65];
  // loss_i = lse - 0.9*z_label - 0.1*mean(z)
  float lv = lser - 0.9f * zd - 0.1f * (slr * (1.0f / 64.0f));
  float lw = lsec - 0.9f * zd - 0.1f * (slc * (1.0f / 64.0f));
  float t = 0.5f * (lv + lw);
#pragma unroll
  for (int s = 1; s < 64; s <<= 1) t += __shfl_xor(t, s);
  if (i == 0) out[0] = t * (1.0f / 64.0f);
}

extern "C" void kernel_launch(void* const* d_in, const int* in_sizes, int n_in,
                              void* d_out, int out_size, void* d_ws, size_t ws_size,
                              hipStream_t stream) {
  (void)in_sizes; (void)n_in; (void)out_size; (void)ws_size;
  const float* video = (const float*)d_in[0];
  const float* wifi  = (const float*)d_in[1];
  const float* scale = (const float*)d_in[2];
  float* dense = (float*)d_ws;   // 4096 f32 scratch

  hipLaunchKernelGGL(pair_kernel, dim3(64 * 64), dim3(512), 0, stream,
                     video, wifi, dense);
  hipLaunchKernelGGL(loss_kernel, dim3(1), dim3(64), 0, stream,
                     dense, scale, (float*)d_out);
}

// Round 4
// 99.987 us; speedup vs baseline: 1.1072x; 1.1072x over previous
//
#include <hip/hip_runtime.h>
#include <hip/hip_bf16.h>

typedef __attribute__((ext_vector_type(8))) short bf16x8;
typedef __attribute__((ext_vector_type(4))) float f32x4;
typedef __attribute__((ext_vector_type(4))) unsigned short u16x4;

#define TT 128
#define DD 256
#define BK 64
#define BPAN 16384   // byte offset of B panel in LDS (panels are 16 KiB each)

__device__ __forceinline__ unsigned short f2bf(float f) {
  unsigned int x = __float_as_uint(f);
  x += 0x7fffu + ((x >> 16) & 1u);          // round-to-nearest-even
  return (unsigned short)(x >> 16);
}

__device__ __forceinline__ bf16x8 pack8(float4 lo, float4 hi) {
  bf16x8 v;
  v[0] = (short)f2bf(lo.x); v[1] = (short)f2bf(lo.y);
  v[2] = (short)f2bf(lo.z); v[3] = (short)f2bf(lo.w);
  v[4] = (short)f2bf(hi.x); v[5] = (short)f2bf(hi.y);
  v[6] = (short)f2bf(hi.z); v[7] = (short)f2bf(hi.w);
  return v;
}

// One-shot f32 -> bf16 preconversion of both feature tensors.
__global__ __launch_bounds__(256) void conv_kernel(
    const float* __restrict__ v, const float* __restrict__ w,
    unsigned short* __restrict__ vb, unsigned short* __restrict__ wb) {
  const int idx = blockIdx.x * 256 + threadIdx.x;   // 0..524287 float4 units
  float4 a = reinterpret_cast<const float4*>(v)[idx];
  float4 b = reinterpret_cast<const float4*>(w)[idx];
  u16x4 pa, pb;
  pa[0] = f2bf(a.x); pa[1] = f2bf(a.y); pa[2] = f2bf(a.z); pa[3] = f2bf(a.w);
  pb[0] = f2bf(b.x); pb[1] = f2bf(b.y); pb[2] = f2bf(b.z); pb[3] = f2bf(b.w);
  reinterpret_cast<u16x4*>(vb)[idx] = pa;
  reinterpret_cast<u16x4*>(wb)[idx] = pb;
}

// One workgroup per (i,j) pair: computes dense_similarity[i,j].
// GEMM: 128x128x256 bf16 MFMA from 16 KiB A/B LDS panels (BK=64, XOR-swizzled).
// Pooling: done DIRECTLY from MFMA accumulators in registers; cross-wave
// combines via ~9 KiB of LDS partials (reusing the panel region).
template <bool PRE>
__global__ __launch_bounds__(512, 6) void pair_kernel(
    const float* __restrict__ videof, const float* __restrict__ wifif,
    const unsigned short* __restrict__ videob, const unsigned short* __restrict__ wifib,
    float* __restrict__ dense) {
  __shared__ __align__(16) char lds[32768];
  const int tid = threadIdx.x;
  const int bid = blockIdx.x;
  const int bi = bid >> 6, bj = bid & 63;

  const int wid = tid >> 6, l = tid & 63;
  const int l15 = l & 15;
  const int R   = (wid >> 1) * 32;          // wave's video-row base
  const int Cc  = (wid & 1) * 64;           // wave's wifi-col base
  const int xr  = (l15 & 7) << 4;           // panel swizzle for frag rows
  const int lhi16 = (l >> 4) * 16;          // lane's 16B k-chunk

  // staging: thread t handles 16 elements of one panel row chunk
  const int srow  = tid >> 2;               // 0..127
  const int scolb = (tid & 3) * 32;         // byte col within 128B panel row
  const int sswz  = (srow & 7) << 4;
  const int sb0 = srow * 128 + ((scolb)      ^ sswz);
  const int sb1 = srow * 128 + ((scolb + 16) ^ sswz);

  f32x4 acc[2][4];
#pragma unroll
  for (int m = 0; m < 2; ++m)
#pragma unroll
    for (int n = 0; n < 4; ++n) acc[m][n] = (f32x4){0.f, 0.f, 0.f, 0.f};

  const int arow0 = (R + l15) * 128;
  const int arow1 = (R + 16 + l15) * 128;
  const int brow0 = (Cc +  0 + l15) * 128 + BPAN;
  const int brow1 = (Cc + 16 + l15) * 128 + BPAN;
  const int brow2 = (Cc + 32 + l15) * 128 + BPAN;
  const int brow3 = (Cc + 48 + l15) * 128 + BPAN;

  for (int kp = 0; kp < 4; ++kp) {
    bf16x8 va0, va1, vb0, vb1;
    if constexpr (PRE) {
      const unsigned short* pa = videob + (size_t)bi * (TT * DD) + srow * DD + kp * BK + (tid & 3) * 16;
      const unsigned short* pb = wifib  + (size_t)bj * (TT * DD) + srow * DD + kp * BK + (tid & 3) * 16;
      va0 = *(const bf16x8*)(pa);
      va1 = *(const bf16x8*)(pa + 8);
      vb0 = *(const bf16x8*)(pb);
      vb1 = *(const bf16x8*)(pb + 8);
    } else {
      const float* pa = videof + (size_t)bi * (TT * DD) + srow * DD + kp * BK + (tid & 3) * 16;
      const float* pb = wifif  + (size_t)bj * (TT * DD) + srow * DD + kp * BK + (tid & 3) * 16;
      float4 a0 = *(const float4*)(pa);
      float4 a1 = *(const float4*)(pa + 4);
      float4 a2 = *(const float4*)(pa + 8);
      float4 a3 = *(const float4*)(pa + 12);
      float4 b0 = *(const float4*)(pb);
      float4 b1 = *(const float4*)(pb + 4);
      float4 b2 = *(const float4*)(pb + 8);
      float4 b3 = *(const float4*)(pb + 12);
      va0 = pack8(a0, a1); va1 = pack8(a2, a3);
      vb0 = pack8(b0, b1); vb1 = pack8(b2, b3);
    }
    if (kp) __syncthreads();                // prev panel fully consumed
    *(bf16x8*)(lds + sb0)        = va0;
    *(bf16x8*)(lds + sb1)        = va1;
    *(bf16x8*)(lds + BPAN + sb0) = vb0;
    *(bf16x8*)(lds + BPAN + sb1) = vb1;
    __syncthreads();                        // panel ready

#pragma unroll
    for (int ks = 0; ks < 2; ++ks) {
      const int ko = (ks * 64 + lhi16) ^ xr;
      bf16x8 fa0 = *(const bf16x8*)(lds + arow0 + ko);
      bf16x8 fa1 = *(const bf16x8*)(lds + arow1 + ko);
      bf16x8 fb0 = *(const bf16x8*)(lds + brow0 + ko);
      bf16x8 fb1 = *(const bf16x8*)(lds + brow1 + ko);
      bf16x8 fb2 = *(const bf16x8*)(lds + brow2 + ko);
      bf16x8 fb3 = *(const bf16x8*)(lds + brow3 + ko);
      acc[0][0] = __builtin_amdgcn_mfma_f32_16x16x32_bf16(fa0, fb0, acc[0][0], 0, 0, 0);
      acc[0][1] = __builtin_amdgcn_mfma_f32_16x16x32_bf16(fa0, fb1, acc[0][1], 0, 0, 0);
      acc[0][2] = __builtin_amdgcn_mfma_f32_16x16x32_bf16(fa0, fb2, acc[0][2], 0, 0, 0);
      acc[0][3] = __builtin_amdgcn_mfma_f32_16x16x32_bf16(fa0, fb3, acc[0][3], 0, 0, 0);
      acc[1][0] = __builtin_amdgcn_mfma_f32_16x16x32_bf16(fa1, fb0, acc[1][0], 0, 0, 0);
      acc[1][1] = __builtin_amdgcn_mfma_f32_16x16x32_bf16(fa1, fb1, acc[1][1], 0, 0, 0);
      acc[1][2] = __builtin_amdgcn_mfma_f32_16x16x32_bf16(fa1, fb2, acc[1][2], 0, 0, 0);
      acc[1][3] = __builtin_amdgcn_mfma_f32_16x16x32_bf16(fa1, fb3, acc[1][3], 0, 0, 0);
    }
  }
  __syncthreads();   // all frag reads done; panel region becomes pooling scratch

  // Pooling scratch (floats, inside former A panel):
  float* F = reinterpret_cast<float*>(lds);
  float* pmax = F;          // [2][128]  row partial max   (per col-half)
  float* pse  = F + 256;    // [2][128]  row partial sum-e
  float* psev = F + 512;    // [2][128]  row partial sum-e*v
  float* cmax = F + 768;    // [4][128]  col partial max   (per row-group)
  float* cse  = F + 1280;   // [4][128]
  float* csev = F + 1792;   // [4][128]
  float* gbuf = F + 2304;   // [2]

  // C/D layout (16x16x32): col = Cc + n*16 + (l&15), row = R + (l>>4)*4 + m*16 + reg
  const int rbase = R + (l >> 4) * 4;

  // ---- Phase A: partial maxes (row over this wave's 64 cols; col over 32 rows)
#pragma unroll
  for (int m = 0; m < 2; ++m)
#pragma unroll
    for (int reg = 0; reg < 4; ++reg) {
      float mx = fmaxf(fmaxf(acc[m][0][reg], acc[m][1][reg]),
                       fmaxf(acc[m][2][reg], acc[m][3][reg]));
      mx = fmaxf(mx, __shfl_xor(mx, 1));
      mx = fmaxf(mx, __shfl_xor(mx, 2));
      mx = fmaxf(mx, __shfl_xor(mx, 4));
      mx = fmaxf(mx, __shfl_xor(mx, 8));
      if (l15 == 0) pmax[(wid & 1) * 128 + rbase + m * 16 + reg] = mx;
    }
#pragma unroll
  for (int n = 0; n < 4; ++n) {
    float mx = acc[0][n][0];
#pragma unroll
    for (int reg = 1; reg < 4; ++reg) mx = fmaxf(mx, acc[0][n][reg]);
#pragma unroll
    for (int reg = 0; reg < 4; ++reg) mx = fmaxf(mx, acc[1][n][reg]);
    mx = fmaxf(mx, __shfl_xor(mx, 16));
    mx = fmaxf(mx, __shfl_xor(mx, 32));
    if (l < 16) cmax[(wid >> 1) * 128 + Cc + n * 16 + l15] = mx;
  }
  __syncthreads();

  // ---- Phase B: exp-sums with global maxes ----
#pragma unroll
  for (int m = 0; m < 2; ++m)
#pragma unroll
    for (int reg = 0; reg < 4; ++reg) {
      const int row = rbase + m * 16 + reg;
      const float mx = fmaxf(pmax[row], pmax[128 + row]);
      float se = 0.f, sev = 0.f;
#pragma unroll
      for (int n = 0; n < 4; ++n) {
        float v = acc[m][n][reg];
        float e = __expf((v - mx) * 2.0f);   // /tau = *2
        se += e; sev += e * v;
      }
      se  += __shfl_xor(se, 1);  se  += __shfl_xor(se, 2);
      se  += __shfl_xor(se, 4);  se  += __shfl_xor(se, 8);
      sev += __shfl_xor(sev, 1); sev += __shfl_xor(sev, 2);
      sev += __shfl_xor(sev, 4); sev += __shfl_xor(sev, 8);
      if (l15 == 0) {
        pse [(wid & 1) * 128 + row] = se;
        psev[(wid & 1) * 128 + row] = sev;
      }
    }
#pragma unroll
  for (int n = 0; n < 4; ++n) {
    const int col = Cc + n * 16 + l15;
    const float mx = fmaxf(fmaxf(cmax[col], cmax[128 + col]),
                           fmaxf(cmax[256 + col], cmax[384 + col]));
    float se = 0.f, sev = 0.f;
#pragma unroll
    for (int m = 0; m < 2; ++m)
#pragma unroll
      for (int reg = 0; reg < 4; ++reg) {
        float v = acc[m][n][reg];
        float e = __expf((v - mx) * 2.0f);
        se += e; sev += e * v;
      }
    se  += __shfl_xor(se, 16);  se  += __shfl_xor(se, 32);
    sev += __shfl_xor(sev, 16); sev += __shfl_xor(sev, 32);
    if (l < 16) {
      cse [(wid >> 1) * 128 + col] = se;
      csev[(wid >> 1) * 128 + col] = sev;
    }
  }
  __syncthreads();

  // ---- Phase C: frame-level softmax pooling -> scalars ----
  if (wid < 2) {
    float a0, a1;
    if (wid == 0) {
      a0 = (psev[l]      + psev[128 + l])      / (pse[l]      + pse[128 + l]);
      a1 = (psev[64 + l] + psev[192 + l])      / (pse[64 + l] + pse[192 + l]);
    } else {
      float s0 = cse[l] + cse[128 + l] + cse[256 + l] + cse[384 + l];
      float v0 = csev[l] + csev[128 + l] + csev[256 + l] + csev[384 + l];
      float s1 = cse[64 + l] + cse[192 + l] + cse[320 + l] + cse[448 + l];
      float v1 = csev[64 + l] + csev[192 + l] + csev[320 + l] + csev[448 + l];
      a0 = v0 / s0; a1 = v1 / s1;
    }
    float mx = fmaxf(a0, a1);
#pragma unroll
    for (int s = 1; s < 64; s <<= 1) mx = fmaxf(mx, __shfl_xor(mx, s));
    float e0 = __expf((a0 - mx) * 2.0f), e1 = __expf((a1 - mx) * 2.0f);
    float se = e0 + e1, sev = e0 * a0 + e1 * a1;
#pragma unroll
    for (int s = 1; s < 64; s <<= 1) { se += __shfl_xor(se, s); sev += __shfl_xor(sev, s); }
    if (l == 0) gbuf[wid] = sev / se;
  }
  __syncthreads();
  if (tid == 0) dense[bid] = 0.5f * (gbuf[0] + gbuf[1]);
}

// Label-smoothed symmetric CE over the 64x64 dense-similarity matrix. f32 out.
__global__ __launch_bounds__(64) void loss_kernel(
    const float* __restrict__ dense, const float* __restrict__ scalep,
    float* __restrict__ out) {
  const int i = threadIdx.x;   // 0..63 — row i and col i
  const float sc = fminf(scalep[0], 40.0f);
  float mxr = -3.4e38f, mxc = -3.4e38f;
  for (int j = 0; j < 64; ++j) {
    mxr = fmaxf(mxr, sc * dense[i * 64 + j]);
    mxc = fmaxf(mxc, sc * dense[j * 64 + i]);
  }
  float ser = 0.f, sec = 0.f, slr = 0.f, slc = 0.f;
  for (int j = 0; j < 64; ++j) {
    float zr = sc * dense[i * 64 + j];
    float zc = sc * dense[j * 64 + i];
    ser += __expf(zr - mxr); sec += __expf(zc - mxc);
    slr += zr;               slc += zc;
  }
  const float lser = mxr + logf(ser);
  const float lsec = mxc + logf(sec);
  const float zd = sc * dense[i * 65];
  float lv = lser - 0.9f * zd - 0.1f * (slr * (1.0f / 64.0f));
  float lw = lsec - 0.9f * zd - 0.1f * (slc * (1.0f / 64.0f));
  float t = 0.5f * (lv + lw);
#pragma unroll
  for (int s = 1; s < 64; s <<= 1) t += __shfl_xor(t, s);
  if (i == 0) out[0] = t * (1.0f / 64.0f);
}

extern "C" void kernel_launch(void* const* d_in, const int* in_sizes, int n_in,
                              void* d_out, int out_size, void* d_ws, size_t ws_size,
                              hipStream_t stream) {
  (void)in_sizes; (void)n_in; (void)out_size;
  const float* video = (const float*)d_in[0];
  const float* wifi  = (const float*)d_in[1];
  const float* scale = (const float*)d_in[2];
  float* dense = (float*)d_ws;                                   // 16 KiB
  unsigned short* vb = (unsigned short*)((char*)d_ws + 16384);   // 4 MiB
  unsigned short* wb = vb + 64 * TT * DD;                        // 4 MiB

  const bool pre = ws_size >= (size_t)16384 + 2u * 64 * TT * DD * 2;
  if (pre) {
    hipLaunchKernelGGL(conv_kernel, dim3(2048), dim3(256), 0, stream,
                       video, wifi, vb, wb);
    hipLaunchKernelGGL((pair_kernel<true>), dim3(64 * 64), dim3(512), 0, stream,
                       video, wifi, vb, wb, dense);
  } else {
    hipLaunchKernelGGL((pair_kernel<false>), dim3(64 * 64), dim3(512), 0, stream,
                       video, wifi, vb, wb, dense);
  }
  hipLaunchKernelGGL(loss_kernel, dim3(1), dim3(64), 0, stream,
                     dense, scale, (float*)d_out);
}